// Round 11
// baseline (105238.098 us; speedup 1.0000x reference)
//
#include <hip/hip_runtime.h>
#include <stdint.h>

typedef short short8 __attribute__((ext_vector_type(8)));
typedef float floatx4 __attribute__((ext_vector_type(4)));
typedef unsigned long long u64;

__device__ __forceinline__ unsigned short f2bf(float f) {
  union { float f; unsigned int i; } v;
  v.f = f;
  unsigned int r = v.i + 0x7fffu + ((v.i >> 16) & 1u);
  return (unsigned short)(r >> 16);
}
__device__ __forceinline__ short8 cvt8(const float4 a, const float4 b) {
  short8 v;
  v[0] = (short)f2bf(a.x); v[1] = (short)f2bf(a.y);
  v[2] = (short)f2bf(a.z); v[3] = (short)f2bf(a.w);
  v[4] = (short)f2bf(b.x); v[5] = (short)f2bf(b.y);
  v[6] = (short)f2bf(b.z); v[7] = (short)f2bf(b.w);
  return v;
}
// NaN-killing clamp: fmaxf(NaN, lo) == lo (v_max_f32, IEEE mode).
__device__ __forceinline__ float sane(float x, float lim) {
  return fminf(fmaxf(x, -lim), lim);
}

// --- same-XCD fast transport: sc0 = L1-bypass, L2-visible -------------------
// All stores physically pass through the XCD-shared L2 (L1 is write-through),
// so an sc0 store is visible to an sc0 load from any CU on the same XCD at
// ~L2 latency, and the L2 copy is always the latest store (no ABA).  This is
// a FAST PATH ONLY: correctness is anchored by a separate agent-scope MIRROR
// buffer (R7-proven MALL transport).  The two buffers are never cross-read.
__device__ __forceinline__ u64 load8_sc0(const void* p) {
  u64 v;
  asm volatile("global_load_dwordx2 %0, %1, off sc0\n\ts_waitcnt vmcnt(0)"
               : "=&v"(v) : "v"(p) : "memory");
  return v;
}
__device__ __forceinline__ short8 load16_sc0_nowait(const void* p) {
  short8 v;
  asm volatile("global_load_dwordx4 %0, %1, off sc0" : "=&v"(v) : "v"(p));
  return v;
}
__device__ __forceinline__ void store16_sc0(void* p, u64 lo, u64 hi) {
  union { u64 u[2]; short8 s; } st;
  st.u[0] = lo; st.u[1] = hi;
  asm volatile("global_store_dwordx4 %0, %1, off sc0"
               :: "v"(p), "v"(st.s) : "memory");
}

extern __shared__ unsigned short lds[];

// ---------------------------------------------------------------------------
// Phase A: gx GEMM (unchanged since R3; bitwise-identical gx).
// ---------------------------------------------------------------------------
template<int K, int XM>
__global__ __launch_bounds__(256)
void gx_gemm(const float* __restrict__ xf,
             const unsigned short* __restrict__ xb,
             const float* __restrict__ wxf,
             const float* __restrict__ wxb,
             float* __restrict__ gx)
{
  unsigned short* As = lds;              // [128][40] bf16
  unsigned short* Bs = lds + 128 * 40;   // [128][40] bf16

  const int M0 = blockIdx.x * 128;
  const int N0 = blockIdx.y * 128;
  const int dir = blockIdx.z;
  const float* wx = dir ? wxb : wxf;
  float* gxd = gx + (long)dir * 16384 * 1536;

  const int tid = threadIdx.x;
  const int lane = tid & 63;
  const int wid = tid >> 6;
  const int q = lane >> 4;
  const int l16 = lane & 15;
  const int wM = (wid >> 1) * 64;
  const int wN = (wid & 1) * 64;

  const int srow = tid >> 1;             // 0..127 staged row
  const int k0 = (tid & 1) * 16;         // half of the 32-wide K-chunk

  floatx4 acc[4][4];
#pragma unroll
  for (int i = 0; i < 4; ++i)
#pragma unroll
    for (int j = 0; j < 4; ++j) acc[i][j] = (floatx4){0.f, 0.f, 0.f, 0.f};

  for (int kk = 0; kk < K; kk += 32) {
    __syncthreads();
    {
      const int mg = M0 + srow;
      if (XM) {
        const float* ap = xf + ((long)(mg & 31) * 512 + (mg >> 5)) * 512 + kk + k0;
        float4 f0 = *(const float4*)(ap);
        float4 f1 = *(const float4*)(ap + 4);
        float4 f2 = *(const float4*)(ap + 8);
        float4 f3 = *(const float4*)(ap + 12);
        *(short8*)(As + srow * 40 + k0)     = cvt8(f0, f1);
        *(short8*)(As + srow * 40 + k0 + 8) = cvt8(f2, f3);
      } else {
        const unsigned short* ap = xb + (long)mg * 1024 + kk + k0;
        *(short8*)(As + srow * 40 + k0)     = *(const short8*)(ap);
        *(short8*)(As + srow * 40 + k0 + 8) = *(const short8*)(ap + 8);
      }
      const float* bp = wx + (long)(N0 + srow) * K + kk + k0;
      float4 g0 = *(const float4*)(bp);
      float4 g1 = *(const float4*)(bp + 4);
      float4 g2 = *(const float4*)(bp + 8);
      float4 g3 = *(const float4*)(bp + 12);
      *(short8*)(Bs + srow * 40 + k0)     = cvt8(g0, g1);
      *(short8*)(Bs + srow * 40 + k0 + 8) = cvt8(g2, g3);
    }
    __syncthreads();
    short8 a[4], b[4];
#pragma unroll
    for (int mt = 0; mt < 4; ++mt)
      a[mt] = *(const short8*)(As + (wM + mt * 16 + l16) * 40 + q * 8);
#pragma unroll
    for (int nt = 0; nt < 4; ++nt)
      b[nt] = *(const short8*)(Bs + (wN + nt * 16 + l16) * 40 + q * 8);
#pragma unroll
    for (int mt = 0; mt < 4; ++mt)
#pragma unroll
      for (int nt = 0; nt < 4; ++nt)
        acc[mt][nt] = __builtin_amdgcn_mfma_f32_16x16x32_bf16(
            a[mt], b[nt], acc[mt][nt], 0, 0, 0);
  }
#pragma unroll
  for (int mt = 0; mt < 4; ++mt) {
    const int row = M0 + wM + mt * 16 + q * 4;
#pragma unroll
    for (int nt = 0; nt < 4; ++nt) {
      const int col = N0 + wN + nt * 16 + l16;
#pragma unroll
      for (int r = 0; r < 4; ++r)
        gxd[(long)(row + r) * 1536 + col] = acc[mt][nt][r];
    }
  }
}

// ---------------------------------------------------------------------------
// Phase B: persistent recurrence (R11 = R7 + same-XCD dual-write fast path).
// 256 blocks x 128 thr; 99.8KB LDS forces 1 block/CU => exactly 32 blocks on
// each XCD.  Blocks read HW_REG_XCC_ID and claim a per-XCD rank; XCD0's 32
// become fw(rank<16)/bw; others exit.  Producers DUAL-WRITE each h fragment:
// sc0 store into ringf (XCD0-local L2 fast path) AND agent-scope atomics
// into ringm (MALL mirror, R7-proven).  Consumers: bounded sc0 canary +
// bounded sc0 validate on ringf; 4 consecutive failures permanently switch
// the wave to the mirror path (R7 verbatim, generously bounded -> a broken
// assumption yields WRONG+VISIBLE results, never a hang).  No buffer is read
// through two transports => the tag-period-4 ABA hazard cannot arise.
// gx prefetch issues AFTER acquisition (matters when exchange is L2-fast).
// ---------------------------------------------------------------------------
template<int OUT>
__global__ __launch_bounds__(128)
void gru_rec(const float* __restrict__ gx,
             const float* __restrict__ whfp, const float* __restrict__ bhfp,
             const float* __restrict__ whbp, const float* __restrict__ bhbp,
             const float* __restrict__ bxfp, const float* __restrict__ bxbp,
             unsigned short* __restrict__ ringf,  // fast ring  [2][2][2][16][64][8]
             unsigned short* __restrict__ ringm,  // mirror ring, same layout
             unsigned short* __restrict__ y0,
             float* __restrict__ omain,
             float* __restrict__ out_hf,          // float [32][512]
             float* __restrict__ out_hb,          // float [32][512]
             int* __restrict__ claims)            // [8] per-XCD rank counters
{
  constexpr u64 TM = 0x4000400040004000ULL;       // bit14 of each bf16
  unsigned short* whs = lds;                      // [96][520]

  // --- role claim: rank within this block's (hardware-read) XCD ---
  int xcd;
  asm("s_getreg_b32 %0, hwreg(HW_REG_XCC_ID)" : "=s"(xcd));
  xcd &= 7;
  int rank_;
  {
    int* ip = (int*)lds;
    if (threadIdx.x == 0) ip[0] = atomicAdd(claims + xcd, 1);
    __syncthreads();
    rank_ = ip[0];
    __syncthreads();                 // lds reusable for whs staging below
  }
  if (xcd != 0 || rank_ >= 32) return;

  const bool fw = rank_ < 16;
  const int d = rank_ & 15;
  const int tid = threadIdx.x;
  const int lane = tid & 63;
  const int w = tid >> 6;
  const int q = lane >> 4;
  const int l16 = lane & 15;

  const float* wh = fw ? whfp : whbp;
  const float* bh = fw ? bhfp : bhbp;
  const float* bx = fw ? bxfp : bxbp;
  const int col0 = d * 32;
  const int dirofs = fw ? 0 : 512;
  const long dirbyte = fw ? 0 : 32768;
  const float* gxd = gx + (long)(fw ? 0 : 1) * 16384 * 1536;

  // stage whs: row lr = g*32 + jc  <-  wh row g*512 + col0 + jc (K=512)
  for (int c = tid; c < 96 * 64; c += 128) {
    int lr = c >> 6, c8 = (c & 63) * 8;
    int g = lr >> 5, jc = lr & 31;
    const float* src = wh + (long)(g * 512 + col0 + jc) * 512 + c8;
    *(short8*)(whs + lr * 520 + c8) =
        cvt8(*(const float4*)src, *(const float4*)(src + 4));
  }
  __syncthreads();

  const int jj = l16;
  float cr[2], cz[2], bxn[2], bhn[2];
#pragma unroll
  for (int n2 = 0; n2 < 2; ++n2) {
    const int cc = col0 + n2 * 16 + jj;
    cr[n2] = bx[cc] + bh[cc];
    cz[n2] = bx[512 + cc] + bh[512 + cc];
    bxn[n2] = bx[1024 + cc];
    bhn[n2] = bh[1024 + cc];
  }

  const int cb = w * 16 + q * 4;      // C-layout batch base
  const floatx4 fz = {0.f, 0.f, 0.f, 0.f};
  float h[2][4] = {{0.f, 0.f, 0.f, 0.f}, {0.f, 0.f, 0.f, 0.f}};
  unsigned int* y032 = (unsigned int*)y0;

  // gx prefetch registers: [g][n2][r] -> 24 floats, one step ahead.
  float nx[24];
  auto load_gx = [&](int t) {
    const float* base = gxd + (long)t * 32 * 1536;
#pragma unroll
    for (int g = 0; g < 3; ++g)
#pragma unroll
      for (int n2 = 0; n2 < 2; ++n2)
#pragma unroll
        for (int r = 0; r < 4; ++r)
          nx[(g * 2 + n2) * 4 + r] = __builtin_nontemporal_load(
              base + (long)(cb + r) * 1536 + g * 512 + col0 + n2 * 16 + jj);
  };
  { const int t0 = fw ? 0 : 511; load_gx(t0); }

  union V { u64 u[2]; short8 s; unsigned int dd[4]; };

  int strikes = 0;
  bool fast_ok = true;                 // per-wave: fast ring usable so far

  for (int it = 0; it < 512; ++it) {
    const int t = fw ? it : 511 - it;
    float cur[24];
#pragma unroll
    for (int i = 0; i < 24; ++i) cur[i] = nx[i];

    floatx4 ar[2] = {fz, fz}, az[2] = {fz, fz}, an[2] = {fz, fz};
    if (it > 0) {
      const int slot_r = (it + 1) & 1;          // slot written at it-1
      const long roff = (long)slot_r * 65536 + dirbyte + (long)w * 16384;
      const char* fwreg = (const char*)ringf + roff;
      const char* mwreg = (const char*)ringm + roff;
      const u64 expectw = ((((it - 1) >> 1) & 1) ^ 1) ? TM : 0ULL;

      short8 af[16];
      bool got = false;

      if (fast_ok) {
        // fast canary: bounded sc0 poll of 64 last-stored words
        const void* cptr = (const void*)(fwreg + (long)l16 * 1024 +
                                         (long)q * 256 + 248);
        bool cdone = false;
        for (int pc = 0; pc < 1024; ++pc) {
          u64 can = load8_sc0(cptr);
          if (__ballot(((can ^ expectw) & TM) != 0) == 0) { cdone = true; break; }
          __builtin_amdgcn_s_sleep(1);
        }
        if (cdone) {
          const char* frb = fwreg + (long)lane * 16;
#pragma unroll
          for (int ks = 0; ks < 16; ++ks)
            af[ks] = load16_sc0_nowait(frb + ks * 1024);
          asm volatile("s_waitcnt vmcnt(0)" ::: "memory");
          __builtin_amdgcn_sched_barrier(0);
          for (int sw = 0; sw < 6 && !got; ++sw) {
            u64 bad = 0;
#pragma unroll
            for (int ks = 0; ks < 16; ++ks) {
              V v; v.s = af[ks];
              bad |= ((v.u[0] ^ expectw) | (v.u[1] ^ expectw)) & TM;
            }
            if (bad == 0) { got = true; break; }
            __builtin_amdgcn_s_sleep(1);
#pragma unroll
            for (int ks = 0; ks < 16; ++ks)
              af[ks] = load16_sc0_nowait(frb + ks * 1024);
            asm volatile("s_waitcnt vmcnt(0)" ::: "memory");
            __builtin_amdgcn_sched_barrier(0);
          }
          if (!got) {
            u64 bad = 0;
#pragma unroll
            for (int ks = 0; ks < 16; ++ks) {
              V v; v.s = af[ks];
              bad |= ((v.u[0] ^ expectw) | (v.u[1] ^ expectw)) & TM;
            }
            if (bad == 0) got = true;
          }
        }
        if (got) strikes = 0;
        else if (++strikes >= 4) fast_ok = false;
      }

      if (!got) {
        // mirror path (R7-proven MALL transport), generously bounded.
        const void* mptr = (const void*)(mwreg + (long)l16 * 1024 +
                                         (long)q * 256 + 248);
        for (int pc = 0; pc < 8192; ++pc) {
          u64 can = __hip_atomic_load((const u64*)mptr, __ATOMIC_RELAXED,
                                      __HIP_MEMORY_SCOPE_AGENT);
          if (__ballot(((can ^ expectw) & TM) != 0) == 0) break;
          __builtin_amdgcn_s_sleep(1);
        }
        const char* mrb = mwreg + (long)lane * 16;
#pragma unroll
        for (int ks = 0; ks < 16; ++ks)
          af[ks] = __builtin_nontemporal_load((const short8*)(mrb + ks * 1024));
        for (int sweep = 0; sweep < 16384; ++sweep) {
          u64 bad = 0;
#pragma unroll
          for (int ks = 0; ks < 16; ++ks) {
            V v; v.s = af[ks];
            bad |= ((v.u[0] ^ expectw) | (v.u[1] ^ expectw)) & TM;
          }
          if (bad == 0) break;
          __builtin_amdgcn_s_sleep(1);
#pragma unroll
          for (int ks = 0; ks < 16; ++ks) {
            u64* p = (u64*)(mrb + ks * 1024);
            V v;
            v.u[0] = __hip_atomic_load(p,     __ATOMIC_RELAXED, __HIP_MEMORY_SCOPE_AGENT);
            v.u[1] = __hip_atomic_load(p + 1, __ATOMIC_RELAXED, __HIP_MEMORY_SCOPE_AGENT);
            af[ks] = v.s;
          }
        }
      }

      // gx prefetch AFTER acquisition (keeps its HBM latency out of polls).
      if (it < 511) {
        const int tn = fw ? it + 1 : 511 - (it + 1);
        load_gx(tn);
      }

#pragma unroll
      for (int ks = 0; ks < 16; ++ks) {
        V v; v.s = af[ks];
        v.dd[0] &= 0xBFFFBFFFu; v.dd[1] &= 0xBFFFBFFFu;
        v.dd[2] &= 0xBFFFBFFFu; v.dd[3] &= 0xBFFFBFFFu;
        short8 a = v.s;
#pragma unroll
        for (int n2 = 0; n2 < 2; ++n2) {
          short8 vr = *(const short8*)(whs + (n2 * 16 + jj) * 520 + ks * 32 + q * 8);
          short8 vz = *(const short8*)(whs + (32 + n2 * 16 + jj) * 520 + ks * 32 + q * 8);
          short8 vn = *(const short8*)(whs + (64 + n2 * 16 + jj) * 520 + ks * 32 + q * 8);
          ar[n2] = __builtin_amdgcn_mfma_f32_16x16x32_bf16(a, vr, ar[n2], 0, 0, 0);
          az[n2] = __builtin_amdgcn_mfma_f32_16x16x32_bf16(a, vz, az[n2], 0, 0, 0);
          an[n2] = __builtin_amdgcn_mfma_f32_16x16x32_bf16(a, vn, an[n2], 0, 0, 0);
        }
      }
    } else {
      load_gx(fw ? 1 : 510);   // it==0: just prefetch next step's gx
    }

    unsigned short hb16[2][4];
#pragma unroll
    for (int n2 = 0; n2 < 2; ++n2) {
#pragma unroll
      for (int r = 0; r < 4; ++r) {
        const float xr = sane(cur[(0 * 2 + n2) * 4 + r] + ar[n2][r] + cr[n2], 60.f);
        const float xz = sane(cur[(1 * 2 + n2) * 4 + r] + az[n2][r] + cz[n2], 60.f);
        const float rr = 1.f / (1.f + __expf(-xr));
        const float zz = 1.f / (1.f + __expf(-xz));
        const float xn = sane(cur[(2 * 2 + n2) * 4 + r] + bxn[n2] +
                              rr * (an[n2][r] + bhn[n2]), 30.f);
        const float e2 = __expf(-2.f * xn);
        const float nn = (1.f - e2) / (1.f + e2);
        h[n2][r] = (1.f - zz) * nn + zz * h[n2][r];
        hb16[n2][r] = f2bf(h[n2][r]);
      }
    }

    // producer: butterfly-pack fragment elements; DUAL-WRITE 16B elements:
    // sc0 into ringf (local-L2 fast path) + agent atomics into ringm.
    {
      const unsigned short utag = (((it >> 1) & 1) ^ 1) ? 0x4000 : 0;
      const int slot_w = it & 1;
      const long soff = (long)slot_w * 65536 + dirbyte + (long)w * 16384;
      char* fsb = (char*)ringf + soff;
      char* msb = (char*)ringm + soff;
      const int o = l16 >> 3;                 // col octet within n2 group
#pragma unroll
      for (int n2 = 0; n2 < 2; ++n2) {
        const int cb2 = col0 + n2 * 16 + o * 8;
        const int ksq = (cb2 >> 5) * 1024 + ((cb2 >> 3) & 3) * 256;
        u64 lo = 0, hi = 0;
#pragma unroll
        for (int r = 0; r < 4; ++r) {
          int tv = (int)(unsigned short)(hb16[n2][r] | utag);
          int pm = __shfl_xor(tv, 1);
          unsigned int pair = (l16 & 1)
              ? ((unsigned)(pm & 0xffff) | ((unsigned)tv << 16))
              : ((unsigned)(tv & 0xffff) | ((unsigned)pm << 16));
          unsigned int pm2 = (unsigned)__shfl_xor((int)pair, 2);
          unsigned int d0 = (l16 & 2) ? pm2 : pair;
          unsigned int d1 = (l16 & 2) ? pair : pm2;
          unsigned int p0 = (unsigned)__shfl_xor((int)d0, 4);
          unsigned int p1 = (unsigned)__shfl_xor((int)d1, 4);
          unsigned int e0 = (l16 & 4) ? p0 : d0;
          unsigned int e1 = (l16 & 4) ? p1 : d1;
          unsigned int e2 = (l16 & 4) ? d0 : p0;
          unsigned int e3 = (l16 & 4) ? d1 : p1;
          if ((l16 & 3) == r) {
            lo = (u64)e0 | ((u64)e1 << 32);
            hi = (u64)e2 | ((u64)e3 << 32);
          }
        }
        if ((l16 & 4) == 0) {
          const long eoff = ksq + (q * 4 + (l16 & 3)) * 16;
          store16_sc0(fsb + eoff, lo, hi);
          u64* mp = (u64*)(msb + eoff);
          __hip_atomic_store(mp,     lo, __ATOMIC_RELAXED, __HIP_MEMORY_SCOPE_AGENT);
          __hip_atomic_store(mp + 1, hi, __ATOMIC_RELAXED, __HIP_MEMORY_SCOPE_AGENT);
        }
      }
    }

    if (OUT == 0) {  // y0 bf16 [S][B][1024], untagged pairs, nt stores
#pragma unroll
      for (int n2 = 0; n2 < 2; ++n2) {
        const int colw = (dirofs + col0 + n2 * 16 + jj) >> 1;
#pragma unroll
        for (int r = 0; r < 4; ++r) {
          int v = hb16[n2][r];
          int pm = __shfl_xor(v, 1);
          unsigned int pr = (unsigned)(v & 0xffff) | ((unsigned)(pm & 0xffff) << 16);
          if ((jj & 1) == 0)
            __builtin_nontemporal_store(pr,
                y032 + ((long)t * 32 + cb + r) * 512 + colw);
        }
      }
    }
    if (OUT == 1) {  // omain f32 [B][S][1024], nt stores
#pragma unroll
      for (int n2 = 0; n2 < 2; ++n2)
#pragma unroll
        for (int r = 0; r < 4; ++r)
          __builtin_nontemporal_store(h[n2][r],
              omain + (long)(cb + r) * 524288 + (long)t * 1024 +
              dirofs + col0 + n2 * 16 + jj);
    }
    if (it == 511) {
      float* oh = fw ? out_hf : out_hb;
#pragma unroll
      for (int n2 = 0; n2 < 2; ++n2)
#pragma unroll
        for (int r = 0; r < 4; ++r)
          oh[(cb + r) * 512 + col0 + n2 * 16 + jj] = h[n2][r];
    }
  }
}

// ---------------------------------------------------------------------------
// ws layout (235,413,504 B ~= 224.5 MiB):
//   gx      @ 0          : 201326592  f32  [2][512][32][1536]
//   y0      @ 201326592  : 33554432   bf16 [512][32][1024]  (plain, no tags)
//   ring0f  @ 234881024  : 131072     fast ring L0   (tagged, zeroed)
//   ring0m  @ 235012096  : 131072     mirror ring L0 (tagged, zeroed)
//   ring1f  @ 235143168  : 131072     fast ring L1   (tagged, zeroed)
//   ring1m  @ 235274240  : 131072     mirror ring L1 (tagged, zeroed)
//   claims0 @ 235405312  : 4096       per-XCD rank counters (zeroed)
//   claims1 @ 235409408  : 4096
// d_out (float32): main [32][512][1024] @0, h_fw @16777216, h_bw @16809984.
// ---------------------------------------------------------------------------
extern "C" void kernel_launch(void* const* d_in, const int* in_sizes, int n_in,
                              void* d_out, int out_size, void* d_ws, size_t ws_size,
                              hipStream_t stream)
{
  (void)in_sizes; (void)n_in; (void)out_size; (void)ws_size;

  const float* x    = (const float*)d_in[0];
  const float* wxf0 = (const float*)d_in[1];
  const float* bxf0 = (const float*)d_in[2];
  const float* whf0 = (const float*)d_in[3];
  const float* bhf0 = (const float*)d_in[4];
  const float* wxb0 = (const float*)d_in[5];
  const float* bxb0 = (const float*)d_in[6];
  const float* whb0 = (const float*)d_in[7];
  const float* bhb0 = (const float*)d_in[8];
  const float* wxf1 = (const float*)d_in[9];
  const float* bxf1 = (const float*)d_in[10];
  const float* whf1 = (const float*)d_in[11];
  const float* bhf1 = (const float*)d_in[12];
  const float* wxb1 = (const float*)d_in[13];
  const float* bxb1 = (const float*)d_in[14];
  const float* whb1 = (const float*)d_in[15];
  const float* bhb1 = (const float*)d_in[16];

  char* ws = (char*)d_ws;
  float* gx              = (float*)(ws);
  unsigned short* y0     = (unsigned short*)(ws + 201326592L);
  unsigned short* ring0f = (unsigned short*)(ws + 234881024L);
  unsigned short* ring0m = (unsigned short*)(ws + 235012096L);
  unsigned short* ring1f = (unsigned short*)(ws + 235143168L);
  unsigned short* ring1m = (unsigned short*)(ws + 235274240L);
  int* claims0           = (int*)(ws + 235405312L);
  int* claims1           = (int*)(ws + 235409408L);

  float* out = (float*)d_out;
  float* out_hf0 = out + 16777216L;
  float* out_hf1 = out + 16777216L + 16384L;
  float* out_hb0 = out + 16777216L + 32768L;
  float* out_hb1 = out + 16777216L + 49152L;

  const size_t lds_gemm = (size_t)(2 * 128 * 40) * 2;   // 20,480 B
  const size_t lds_rec  = (size_t)(96 * 520) * 2;       // 99,840 B
  (void)hipFuncSetAttribute((const void*)gru_rec<0>,
                            hipFuncAttributeMaxDynamicSharedMemorySize, (int)lds_rec);
  (void)hipFuncSetAttribute((const void*)gru_rec<1>,
                            hipFuncAttributeMaxDynamicSharedMemorySize, (int)lds_rec);

  // zero rings + claim counters (y0 plain; gx needs no init)
  hipMemsetAsync(ws + 234881024L, 0, 532480L, stream);

  // L0 phase A: gx0[dir][t*32+b][1536] from x f32
  gx_gemm<512, 1><<<dim3(128, 12, 2), dim3(256), lds_gemm, stream>>>(
      x, nullptr, wxf0, wxb0, gx);
  // L0 phase B: recurrence -> y0 bf16 (+ h outputs)
  gru_rec<0><<<dim3(256), dim3(128), lds_rec, stream>>>(
      gx, whf0, bhf0, whb0, bhb0, bxf0, bxb0,
      ring0f, ring0m, y0, nullptr, out_hf0, out_hb0, claims0);
  // L1 phase A: gx1 from y0 bf16
  gx_gemm<1024, 0><<<dim3(128, 12, 2), dim3(256), lds_gemm, stream>>>(
      nullptr, y0, wxf1, wxb1, gx);
  // L1 phase B: recurrence -> omain f32 (+ h outputs)
  gru_rec<1><<<dim3(256), dim3(128), lds_rec, stream>>>(
      gx, whf1, bhf1, whb1, bhb1, bxf1, bxb1,
      ring1f, ring1m, nullptr, out, out_hf1, out_hb1, claims1);
}